// Round 9
// baseline (852.350 us; speedup 1.0000x reference)
//
#include <hip/hip_runtime.h>
#include <hip/hip_bf16.h>

typedef __bf16 bf16;
typedef __bf16 bf16x8 __attribute__((ext_vector_type(8)));
typedef float f32x4 __attribute__((ext_vector_type(4)));
typedef unsigned int u32x2 __attribute__((ext_vector_type(2)));

#define DEVI static __device__ __forceinline__

static constexpr int Bn = 4, Cc = 192, Hh = 256, Wd = 256;
static constexpr int NHd = 6, HD = 32;
static constexpr int Mtot = Bn * Hh * Wd;          // 262144 pixels
static constexpr int PD = 264;                     // padded spatial dim (4+256+4)
static constexpr size_t BPv = (size_t)Bn * PD * PD;   // per-d Vt plane elems = 278784
static constexpr size_t KHP = BPv * HD;               // per-head Kp elems = 8921088
static constexpr float EPSv = 1e-5f;

DEVI f32x4 mfma16(bf16x8 a, bf16x8 b, f32x4 c) {
    return __builtin_amdgcn_mfma_f32_16x16x32_bf16(a, b, c, 0, 0, 0);
}

DEVI unsigned cvtpk_bf16(float lo, float hi) {
    unsigned r;
    asm("v_cvt_pk_bf16_f32 %0, %1, %2" : "=v"(r) : "v"(lo), "v"(hi));
    return r;
}

// ---------------------------------------------------------------- K0: weights
__global__ __launch_bounds__(256) void k_prep(const float* Wq, const float* Wkv,
                                              const float* Wo, bf16* WT, bf16* WoT) {
    int idx = blockIdx.x * 256 + threadIdx.x;
    if (idx < 576 * 192) {
        int n = idx / 192, k = idx % 192;
        float v = (n < 192) ? Wq[k * 192 + n] : Wkv[k * 384 + (n - 192)];
        WT[idx] = (bf16)v;
    } else if (idx < 576 * 192 + 192 * 192) {
        int j = idx - 576 * 192;
        int n = j / 192, k = j % 192;
        WoT[j] = (bf16)Wo[k * 192 + n];
    }
}

// ---------------------------------------------------------------- K0b: border fill
// Fill the 4-wide borders of Kp (K-bias row) and Vt (V-bias scalar).
// 6 heads x 4 b x 4160 border cells = 99840 cells.
__global__ __launch_bounds__(256) void k_pad(const float* __restrict__ bkv,
                                             bf16* __restrict__ Kp,
                                             bf16* __restrict__ Vtp) {
    int idx = blockIdx.x * 256 + threadIdx.x;
    if (idx >= 99840) return;
    int head = idx / 16640;
    int r1 = idx % 16640;
    int b = r1 / 4160, c = r1 % 4160;
    int php, pwp;
    if (c < 2112) { int rr = c / 264; php = (rr < 4) ? rr : 256 + rr; pwp = c % 264; }
    else { int j = c - 2112; php = 4 + j / 8; int cc = j % 8; pwp = (cc < 4) ? cc : 256 + cc; }
    size_t cell = (size_t)(b * PD + php) * PD + pwp;
    // K: 32 bf16 bias row
    bf16* kc = Kp + (size_t)head * KHP + cell * HD;
#pragma unroll
    for (int d0 = 0; d0 < 32; d0 += 8) {
        bf16x8 v;
#pragma unroll
        for (int j = 0; j < 8; ++j) v[j] = (bf16)bkv[head * HD + d0 + j];
        *(bf16x8*)(kc + d0) = v;
    }
    // Vt: scalar bias per d-plane
    bf16* vc = Vtp + (size_t)head * HD * BPv + cell;
#pragma unroll
    for (int d = 0; d < 32; ++d) vc[d * BPv] = (bf16)bkv[Cc + head * HD + d];
}

// ---------------------------------------------------------------- K1: fused LN + QKV projection
// As r8 (nt-outer, W read once) but K goes to the padded plane and V to the
// transposed padded plane.
__global__ __launch_bounds__(256) void k_lnqkv(const float* __restrict__ x,
                                               const float* __restrict__ gamma,
                                               const float* __restrict__ beta,
                                               const bf16* __restrict__ WT,
                                               const float* __restrict__ bq,
                                               const float* __restrict__ bkv,
                                               bf16* __restrict__ Qp,
                                               bf16* __restrict__ Kp,
                                               bf16* __restrict__ Vtp) {
    constexpr int AS = 200;
    __shared__ __align__(16) bf16 A[64 * AS];
    __shared__ float red[2][4][64];
    __shared__ float sg[Cc], sbv[Cc];

    int tid = threadIdx.x;
    int q = tid >> 6, p = tid & 63;
    int base = blockIdx.x * 64;
    int b = base >> 16;
    int hw = base & 65535;
    int h = hw >> 8, w0v = hw & 255;
    if (tid < Cc) { sg[tid] = gamma[tid]; sbv[tid] = beta[tid]; }

    const float* xb = x + ((size_t)(b * Cc + q * 48) * Hh + h) * Wd + w0v + p;
    float s = 0.f, s2 = 0.f;
#pragma unroll
    for (int i0 = 0; i0 < 48; i0 += 8) {
        bf16x8 o;
#pragma unroll
        for (int j = 0; j < 8; ++j) {
            float v = xb[(size_t)(i0 + j) * Hh * Wd];
            s += v; s2 += v * v; o[j] = (bf16)v;
        }
        *(bf16x8*)&A[p * AS + q * 48 + i0] = o;
    }
    red[0][q][p] = s; red[1][q][p] = s2;
    __syncthreads();
    float mu = (red[0][0][p] + red[0][1][p] + red[0][2][p] + red[0][3][p]) * (1.f / 192.f);
    float m2 = (red[1][0][p] + red[1][1][p] + red[1][2][p] + red[1][3][p]) * (1.f / 192.f);
    float rs = rsqrtf(m2 - mu * mu + EPSv);
#pragma unroll
    for (int i0 = 0; i0 < 48; i0 += 8) {
        bf16x8 v8 = *(bf16x8*)&A[p * AS + q * 48 + i0];
        bf16x8 o;
#pragma unroll
        for (int j = 0; j < 8; ++j) {
            int c = q * 48 + i0 + j;
            o[j] = (bf16)(((float)v8[j] - mu) * rs * sg[c] + sbv[c]);
        }
        *(bf16x8*)&A[p * AS + q * 48 + i0] = o;
    }
    __syncthreads();

    int lane = tid & 63, l15 = lane & 15, g = lane >> 4;
    const bf16* Wbase = WT + (size_t)(q * 144 + l15) * Cc + g * 8;
#pragma unroll 1
    for (int nt = 0; nt < 9; ++nt) {
        f32x4 acc[4] = {};
        const bf16* wp = Wbase + (size_t)nt * 16 * Cc;
#pragma unroll
        for (int kk = 0; kk < 6; ++kk) {
            bf16x8 wb = *(const bf16x8*)(wp + kk * 32);
#pragma unroll
            for (int mt = 0; mt < 4; ++mt) {
                bf16x8 a = *(bf16x8*)&A[(mt * 16 + l15) * AS + kk * 32 + g * 8];
                acc[mt] = mfma16(wb, a, acc[mt]);   // D[n][pix]
            }
        }
        int n0 = q * 144 + nt * 16 + g * 4;
        const float* bsrc = (n0 < 192) ? (bq + n0) : (bkv + n0 - 192);
        f32x4 b4 = *(const f32x4*)bsrc;
        if (n0 < 192) {                              // Q plane, pixel-major
            bf16* outp = Qp + (size_t)(n0 >> 5) * Mtot * HD + (n0 & 31);
#pragma unroll
            for (int mt = 0; mt < 4; ++mt) {
                u32x2 pk;
                pk[0] = cvtpk_bf16(acc[mt][0] + b4[0], acc[mt][1] + b4[1]);
                pk[1] = cvtpk_bf16(acc[mt][2] + b4[2], acc[mt][3] + b4[3]);
                *(u32x2*)(outp + (size_t)(base + mt * 16 + l15) * HD) = pk;
            }
        } else if (n0 < 384) {                       // K padded plane
            int kh = (n0 - 192) >> 5;
            bf16* outp = Kp + (size_t)kh * KHP
                         + ((size_t)(b * PD + h + 4) * PD) * HD + (n0 & 31);
#pragma unroll
            for (int mt = 0; mt < 4; ++mt) {
                u32x2 pk;
                pk[0] = cvtpk_bf16(acc[mt][0] + b4[0], acc[mt][1] + b4[1]);
                pk[1] = cvtpk_bf16(acc[mt][2] + b4[2], acc[mt][3] + b4[3]);
                *(u32x2*)(outp + (size_t)(w0v + mt * 16 + l15 + 4) * HD) = pk;
            }
        } else {                                     // Vt transposed padded plane
            int vh = (n0 - 384) >> 5;
            int d0 = (n0 - 384) & 31;
            bf16* outp = Vtp + (size_t)vh * HD * BPv + (size_t)d0 * BPv
                         + (size_t)(b * PD + h + 4) * PD + 4 + w0v;
#pragma unroll
            for (int mt = 0; mt < 4; ++mt) {
                int wp2 = mt * 16 + l15;
#pragma unroll
                for (int r = 0; r < 4; ++r)
                    outp[(size_t)r * BPv + wp2] = (bf16)(acc[mt][r] + b4[r]);
            }
        }
    }
}

// ---------------------------------------------------------------- K2: attention
// Branch-free, barrier-free. One block per (head, window); 4 waves x 16 q-rows.
// K from padded plane (no masks); V fragments directly from transposed padded
// plane (no LDS staging). LDS = P only (33.8KB -> 4 blocks/CU).
__global__ __launch_bounds__(256) void k_attn(const bf16* __restrict__ Qp,
                                              const bf16* __restrict__ Kp,
                                              const bf16* __restrict__ Vtp,
                                              bf16* __restrict__ O) {
    constexpr int PS = 264;                        // stride: 4 words mod 32 -> even banks
    int bid = blockIdx.x;
    bid = (bid & 7) * 3072 + (bid >> 3);          // chunked XCD swizzle
    int head = bid >> 12;
    int win = bid & 4095;
    int b = win >> 10, wloc = win & 1023;
    int h0 = ((wloc >> 5) << 3), w0 = ((wloc & 31) << 3);

    int tid = threadIdx.x, wave = tid >> 6, lane = tid & 63;
    int l15 = lane & 15, g = lane >> 4;

    const bf16* Qh = Qp + (size_t)head * Mtot * HD;
    const bf16* Kh = Kp + (size_t)head * KHP;
    const bf16* Vth = Vtp + (size_t)head * HD * BPv;
    bf16* Oh = O + (size_t)head * Mtot * HD;

    __shared__ __align__(16) bf16 P[64 * PS];

    // ---- Q fragment: lane l15 holds Q row wave*16+l15
    int qr = wave * 16 + l15;
    size_t qpix = (size_t)(b * Hh + h0 + (qr >> 3)) * Wd + w0 + (qr & 7);
    bf16x8 aq = *(const bf16x8*)(Qh + qpix * HD + g * 8);

    // ---- S^T = K @ Q^T : 16 kv-tiles, padded K -> no masks
    f32x4 s[16];
    const f32x4 z = {0.f, 0.f, 0.f, 0.f};
    const bf16* kp = Kh + ((size_t)(b * PD + h0) * PD + (w0 + l15)) * HD + g * 8;
#pragma unroll
    for (int t = 0; t < 16; ++t) {
        bf16x8 kf = *(const bf16x8*)(kp + (size_t)t * PD * HD);
        s[t] = mfma16(kf, aq, z);
    }

    // ---- softmax: lane owns row q=l15 (64 of 256 kv; rest in xor-16/32 lanes)
    const float sc = 0.17677669529663689f * 1.4426950408889634f; // scale * log2(e)
    float mr0 = fmaxf(s[0][0], s[0][1]), mr1 = fmaxf(s[0][2], s[0][3]);
#pragma unroll
    for (int t = 1; t < 16; ++t) {
        mr0 = fmaxf(mr0, fmaxf(s[t][0], s[t][1]));
        mr1 = fmaxf(mr1, fmaxf(s[t][2], s[t][3]));
    }
    float m = fmaxf(mr0, mr1);
    m = fmaxf(m, __shfl_xor(m, 16));
    m = fmaxf(m, __shfl_xor(m, 32));
    float nms = -m * sc;
    float sr0 = 0.f, sr1 = 0.f, sr2 = 0.f, sr3 = 0.f;
    int prow = wave * 16 + l15;
#pragma unroll
    for (int t = 0; t < 16; ++t) {
        float p0 = __builtin_amdgcn_exp2f(fmaf(s[t][0], sc, nms));
        float p1 = __builtin_amdgcn_exp2f(fmaf(s[t][1], sc, nms));
        float p2 = __builtin_amdgcn_exp2f(fmaf(s[t][2], sc, nms));
        float p3 = __builtin_amdgcn_exp2f(fmaf(s[t][3], sc, nms));
        sr0 += p0; sr1 += p1; sr2 += p2; sr3 += p3;
        u32x2 pk;
        pk[0] = cvtpk_bf16(p0, p1);
        pk[1] = cvtpk_bf16(p2, p3);
        *(u32x2*)&P[prow * PS + t * 16 + g * 4] = pk;
    }
    float sum = (sr0 + sr1) + (sr2 + sr3);
    sum += __shfl_xor(sum, 16);
    sum += __shfl_xor(sum, 32);
    float inv = __builtin_amdgcn_rcpf(sum);
    __builtin_amdgcn_wave_barrier();   // P rows are wave-private; ordering only

    // ---- O = P @ V : V^T fragments straight from global (L2-hot), no masks
    f32x4 o[2] = {};
    const bf16* vbase = Vth + (size_t)(b * PD + h0) * PD + w0 + 8 * (g & 1)
                        + (size_t)(g >> 1) * PD + (size_t)l15 * BPv;
#pragma unroll
    for (int kk = 0; kk < 8; ++kk) {
        bf16x8 ap = *(const bf16x8*)(&P[prow * PS + kk * 32 + g * 8]);
#pragma unroll
        for (int nt = 0; nt < 2; ++nt) {
            bf16x8 bv = *(const bf16x8*)(vbase + (size_t)nt * 16 * BPv + (size_t)(2 * kk) * PD);
            o[nt] = mfma16(ap, bv, o[nt]);
        }
    }
    float invr[4];
#pragma unroll
    for (int r = 0; r < 4; ++r)
        invr[r] = __shfl(inv, (lane & 48) | (g * 4 + r));
#pragma unroll
    for (int nt = 0; nt < 2; ++nt)
#pragma unroll
        for (int r = 0; r < 4; ++r) {
            int row = wave * 16 + g * 4 + r;
            size_t pix = (size_t)(b * Hh + h0 + (row >> 3)) * Wd + w0 + (row & 7);
            Oh[pix * HD + nt * 16 + l15] = (bf16)(o[nt][r] * invr[r]);
        }
}

// ---------------------------------------------------------------- K3: O-proj + residual (BHWC->BCHW)
__global__ __launch_bounds__(256) void k_out(const bf16* __restrict__ AO,
                                             const bf16* __restrict__ WoT,
                                             const float* __restrict__ bo,
                                             const float* __restrict__ x,
                                             float* __restrict__ out) {
    int row0 = blockIdx.x * 64;
    int tid = threadIdx.x, wave = tid >> 6, lane = tid & 63;
    int l15 = lane & 15, g = lane >> 4;
    int nb = wave * 48;
    f32x4 acc[4][3] = {};
    const bf16* Arow[4];
#pragma unroll
    for (int mt = 0; mt < 4; ++mt) Arow[mt] = AO + (size_t)(row0 + mt * 16 + l15) * HD + g * 8;
    const bf16* Wrow[3];
#pragma unroll
    for (int nt = 0; nt < 3; ++nt) Wrow[nt] = WoT + (size_t)(nb + nt * 16 + l15) * Cc + g * 8;
#pragma unroll
    for (int kk = 0; kk < 6; ++kk) {
        bf16x8 a[4];
#pragma unroll
        for (int mt = 0; mt < 4; ++mt)
            a[mt] = *(const bf16x8*)(Arow[mt] + (size_t)kk * Mtot * HD);
#pragma unroll
        for (int nt = 0; nt < 3; ++nt) {
            bf16x8 bb = *(const bf16x8*)(Wrow[nt] + kk * 32);
#pragma unroll
            for (int mt = 0; mt < 4; ++mt) acc[mt][nt] = mfma16(a[mt], bb, acc[mt][nt]);
        }
    }
    __shared__ float st[192 * 65];
#pragma unroll
    for (int nt = 0; nt < 3; ++nt) {
        float bval = bo[nb + nt * 16 + l15];
#pragma unroll
        for (int mt = 0; mt < 4; ++mt)
#pragma unroll
            for (int r = 0; r < 4; ++r) {
                int ccol = nb + nt * 16 + l15;
                int px = mt * 16 + g * 4 + r;
                st[ccol * 65 + px] = acc[mt][nt][r] + bval;
            }
    }
    __syncthreads();
    int bb2 = row0 / (Hh * Wd);
    int rem = row0 % (Hh * Wd);
    int h = rem / Wd, wstart = rem % Wd;
    for (int idx = tid; idx < 192 * 64; idx += 256) {
        int cc = idx >> 6, px = idx & 63;
        size_t ga = ((size_t)(bb2 * Cc + cc) * Hh + h) * Wd + wstart + px;
        out[ga] = st[cc * 65 + px] + x[ga];
    }
}

// ---------------------------------------------------------------- launch
extern "C" void kernel_launch(void* const* d_in, const int* in_sizes, int n_in,
                              void* d_out, int out_size, void* d_ws, size_t ws_size,
                              hipStream_t stream) {
    const float* x     = (const float*)d_in[0];
    const float* gamma = (const float*)d_in[1];
    const float* beta  = (const float*)d_in[2];
    const float* Wq    = (const float*)d_in[3];
    const float* bq    = (const float*)d_in[4];
    const float* Wkv   = (const float*)d_in[5];
    const float* bkv   = (const float*)d_in[6];
    const float* Wo    = (const float*)d_in[7];
    const float* bo    = (const float*)d_in[8];
    float* out = (float*)d_out;

    char* ws = (char*)d_ws;
    constexpr size_t QSZ  = (size_t)Mtot * HD * 2 * NHd;    // 100663296
    constexpr size_t KSZ  = KHP * 2 * NHd;                  // 107053056
    constexpr size_t VSZ  = KSZ;                            // 107053056
    bf16* Qp  = (bf16*)(ws);
    bf16* Kp  = (bf16*)(ws + QSZ);
    bf16* Vtp = (bf16*)(ws + QSZ + KSZ);
    bf16* AO  = (bf16*)(ws + QSZ + KSZ + VSZ);              // 100663296
    bf16* WT  = (bf16*)(ws + QSZ + KSZ + VSZ + QSZ);        // 221184
    bf16* WoT = (bf16*)(ws + QSZ + KSZ + VSZ + QSZ + 221184);

    k_prep<<<576, 256, 0, stream>>>(Wq, Wkv, Wo, WT, WoT);
    k_pad<<<390, 256, 0, stream>>>(bkv, Kp, Vtp);
    k_lnqkv<<<Mtot / 64, 256, 0, stream>>>(x, gamma, beta, WT, bq, bkv, Qp, Kp, Vtp);
    k_attn<<<4096 * NHd, 256, 0, stream>>>(Qp, Kp, Vtp, AO);
    k_out<<<Mtot / 64, 256, 0, stream>>>(AO, WoT, bo, x, out);
}

// Round 11
// 513.682 us; speedup vs baseline: 1.6593x; 1.6593x over previous
//
#include <hip/hip_runtime.h>
#include <hip/hip_bf16.h>

typedef __bf16 bf16;
typedef __bf16 bf16x8 __attribute__((ext_vector_type(8)));
typedef float f32x4 __attribute__((ext_vector_type(4)));
typedef unsigned int u32x2 __attribute__((ext_vector_type(2)));
typedef unsigned int u32x4 __attribute__((ext_vector_type(4)));

#define DEVI static __device__ __forceinline__

static constexpr int Bn = 4, Cc = 192, Hh = 256, Wd = 256;
static constexpr int NHd = 6, HD = 32;
static constexpr int Mtot = Bn * Hh * Wd;          // 262144 pixels
static constexpr float EPSv = 1e-5f;

DEVI f32x4 mfma16(bf16x8 a, bf16x8 b, f32x4 c) {
    return __builtin_amdgcn_mfma_f32_16x16x32_bf16(a, b, c, 0, 0, 0);
}

DEVI f32x4 mfma16f8(long long a, long long b, f32x4 c) {
    return __builtin_amdgcn_mfma_f32_16x16x32_fp8_fp8(a, b, c, 0, 0, 0);
}

DEVI unsigned cvtpk_bf16(float lo, float hi) {
    unsigned r;
    asm("v_cvt_pk_bf16_f32 %0, %1, %2" : "=v"(r) : "v"(lo), "v"(hi));
    return r;
}

template <bool HIGH>
DEVI unsigned cvtpk_fp8(float lo, float hi, unsigned old) {
    return (unsigned)__builtin_amdgcn_cvt_pk_fp8_f32(lo, hi, (int)old, HIGH);
}

// ---------------------------------------------------------------- K0: weights
// WT576[n][k]: rows 0..191 = Wq^T, rows 192..575 = Wkv^T.  WoT[n][k] = Wo^T.
__global__ __launch_bounds__(256) void k_prep(const float* Wq, const float* Wkv,
                                              const float* Wo, bf16* WT, bf16* WoT) {
    int idx = blockIdx.x * 256 + threadIdx.x;
    if (idx < 576 * 192) {
        int n = idx / 192, k = idx % 192;
        float v = (n < 192) ? Wq[k * 192 + n] : Wkv[k * 384 + (n - 192)];
        WT[idx] = (bf16)v;
    } else if (idx < 576 * 192 + 192 * 192) {
        int j = idx - 576 * 192;
        int n = j / 192, k = j % 192;
        WoT[j] = (bf16)Wo[k * 192 + n];
    }
}

// ---------------------------------------------------------------- K1: fused LN + QKV projection
// r8 structure (nt-outer, W read once). Q,K -> bf16 planes; V -> fp8 plane.
__global__ __launch_bounds__(256) void k_lnqkv(const float* __restrict__ x,
                                               const float* __restrict__ gamma,
                                               const float* __restrict__ beta,
                                               const bf16* __restrict__ WT,
                                               const float* __restrict__ bq,
                                               const float* __restrict__ bkv,
                                               bf16* __restrict__ QK,
                                               unsigned char* __restrict__ V8) {
    constexpr int AS = 200;                       // A-tile stride
    __shared__ __align__(16) bf16 A[64 * AS];
    __shared__ float red[2][4][64];
    __shared__ float sg[Cc], sbv[Cc];

    int tid = threadIdx.x;
    int q = tid >> 6, p = tid & 63;
    int base = blockIdx.x * 64;
    int b = base >> 16;
    int hw = base & 65535;
    int h = hw >> 8, w0 = hw & 255;
    if (tid < Cc) { sg[tid] = gamma[tid]; sbv[tid] = beta[tid]; }

    // pass 1: 48 channels per wave; stats in f32, stash bf16 copy in A
    const float* xb = x + ((size_t)(b * Cc + q * 48) * Hh + h) * Wd + w0 + p;
    float s = 0.f, s2 = 0.f;
#pragma unroll
    for (int i0 = 0; i0 < 48; i0 += 8) {
        bf16x8 o;
#pragma unroll
        for (int j = 0; j < 8; ++j) {
            float v = xb[(size_t)(i0 + j) * Hh * Wd];
            s += v; s2 += v * v; o[j] = (bf16)v;
        }
        *(bf16x8*)&A[p * AS + q * 48 + i0] = o;
    }
    red[0][q][p] = s; red[1][q][p] = s2;
    __syncthreads();
    float mu = (red[0][0][p] + red[0][1][p] + red[0][2][p] + red[0][3][p]) * (1.f / 192.f);
    float m2 = (red[1][0][p] + red[1][1][p] + red[1][2][p] + red[1][3][p]) * (1.f / 192.f);
    float rs = rsqrtf(m2 - mu * mu + EPSv);
    // pass 2: normalize in place
#pragma unroll
    for (int i0 = 0; i0 < 48; i0 += 8) {
        bf16x8 v8 = *(bf16x8*)&A[p * AS + q * 48 + i0];
        bf16x8 o;
#pragma unroll
        for (int j = 0; j < 8; ++j) {
            int c = q * 48 + i0 + j;
            o[j] = (bf16)(((float)v8[j] - mu) * rs * sg[c] + sbv[c]);
        }
        *(bf16x8*)&A[p * AS + q * 48 + i0] = o;
    }
    __syncthreads();

    // GEMM: 4 waves x 144 cols; nt streamed OUTER (W read once), mt inner.
    int lane = tid & 63, l15 = lane & 15, g = lane >> 4;
    const bf16* Wbase = WT + (size_t)(q * 144 + l15) * Cc + g * 8;
#pragma unroll 1
    for (int nt = 0; nt < 9; ++nt) {
        f32x4 acc[4] = {};
        const bf16* wp = Wbase + (size_t)nt * 16 * Cc;
#pragma unroll
        for (int kk = 0; kk < 6; ++kk) {
            bf16x8 wb = *(const bf16x8*)(wp + kk * 32);
#pragma unroll
            for (int mt = 0; mt < 4; ++mt) {
                bf16x8 a = *(bf16x8*)&A[(mt * 16 + l15) * AS + kk * 32 + g * 8];
                acc[mt] = mfma16(wb, a, acc[mt]);   // D[n][pix]
            }
        }
        int n0 = q * 144 + nt * 16 + g * 4;         // 4-group never crosses plane
        const float* bsrc = (n0 < 192) ? (bq + n0) : (bkv + n0 - 192);
        f32x4 b4 = *(const f32x4*)bsrc;
        if (n0 < 384) {                              // Q or K bf16 plane
            bf16* outp = QK + (size_t)(n0 >> 5) * Mtot * HD + (n0 & 31);
#pragma unroll
            for (int mt = 0; mt < 4; ++mt) {
                u32x2 pk;
                pk[0] = cvtpk_bf16(acc[mt][0] + b4[0], acc[mt][1] + b4[1]);
                pk[1] = cvtpk_bf16(acc[mt][2] + b4[2], acc[mt][3] + b4[3]);
                *(u32x2*)(outp + (size_t)(base + mt * 16 + l15) * HD) = pk;
            }
        } else {                                     // V fp8 plane
            int vh = (n0 - 384) >> 5;
            unsigned char* outp = V8 + (size_t)vh * Mtot * HD + ((n0 - 384) & 31);
#pragma unroll
            for (int mt = 0; mt < 4; ++mt) {
                unsigned pk = 0;
                pk = cvtpk_fp8<false>(acc[mt][0] + b4[0], acc[mt][1] + b4[1], pk);
                pk = cvtpk_fp8<true>(acc[mt][2] + b4[2], acc[mt][3] + b4[3], pk);
                *(unsigned*)(outp + (size_t)(base + mt * 16 + l15) * HD) = pk;
            }
        }
    }
}

// ---------------------------------------------------------------- K2: attention
// r8 structure; PV pair (P, V^T) carried in fp8 -> LDS 25.9KB -> 4 blocks/CU.
__global__ __launch_bounds__(256) void k_attn(const bf16* __restrict__ QK,
                                              const unsigned char* __restrict__ V8,
                                              const float* __restrict__ bkv,
                                              bf16* __restrict__ O) {
    constexpr int PS = 272;                        // P row stride BYTES (8B aligned)
    constexpr int VS = 264;                        // VT row stride BYTES
    int bid = blockIdx.x;
    bid = (bid & 7) * 3072 + (bid >> 3);          // chunked XCD swizzle (24576 = 8*3072)
    int head = bid >> 12;                          // /4096
    int win = bid & 4095;
    int b = win >> 10, wloc = win & 1023;
    int h0 = ((wloc >> 5) << 3), w0 = ((wloc & 31) << 3);
    bool interior = (h0 != 0) && (h0 != Hh - 8) && (w0 != 0) && (w0 != Wd - 8);

    int tid = threadIdx.x, wave = tid >> 6, lane = tid & 63;
    int l15 = lane & 15, g = lane >> 4;

    const bf16* Qh = QK + (size_t)head * Mtot * HD;
    const bf16* Kh = QK + (size_t)(6 + head) * Mtot * HD;
    const unsigned char* Vh = V8 + (size_t)head * Mtot * HD;
    bf16* Oh = O + (size_t)head * Mtot * HD;
    long long p00 = (long long)(b * Hh + h0 - 4) * Wd + (w0 - 4);

    __shared__ __align__(16) unsigned char VT8[32 * VS];  // fp8 V^T [d][kv]
    __shared__ __align__(16) unsigned char P8[64 * PS];   // fp8 probs [qrow][kv]

    // ---- stage V^T (one kv row per thread), fp8
    {
        int r = tid;
        unsigned wv[8];
        if (interior) {
            const unsigned char* vr = Vh + (p00 + (r >> 4) * Wd + (r & 15)) * HD;
            u32x4 a0 = *(const u32x4*)(vr);
            u32x4 a1 = *(const u32x4*)(vr + 16);
#pragma unroll
            for (int w = 0; w < 4; ++w) { wv[w] = a0[w]; wv[w + 4] = a1[w]; }
        } else {
            int ph = h0 - 4 + (r >> 4), pw = w0 - 4 + (r & 15);
            bool ok = ((unsigned)ph < (unsigned)Hh) && ((unsigned)pw < (unsigned)Wd);
            long long pix = ok ? ((long long)(b * Hh + ph) * Wd + pw) : 0;
            const unsigned char* vr = Vh + pix * HD;
            u32x4 a0 = *(const u32x4*)(vr);
            u32x4 a1 = *(const u32x4*)(vr + 16);
            const float* vb = bkv + Cc + head * HD;
#pragma unroll
            for (int w = 0; w < 8; ++w) {
                unsigned bw = 0;
                bw = cvtpk_fp8<false>(vb[4 * w], vb[4 * w + 1], bw);
                bw = cvtpk_fp8<true>(vb[4 * w + 2], vb[4 * w + 3], bw);
                unsigned lw = (w < 4) ? a0[w] : a1[w - 4];
                wv[w] = ok ? lw : bw;
            }
        }
#pragma unroll
        for (int w = 0; w < 8; ++w) {
            unsigned word = wv[w];
            VT8[(4 * w + 0) * VS + r] = (unsigned char)(word);
            VT8[(4 * w + 1) * VS + r] = (unsigned char)(word >> 8);
            VT8[(4 * w + 2) * VS + r] = (unsigned char)(word >> 16);
            VT8[(4 * w + 3) * VS + r] = (unsigned char)(word >> 24);
        }
    }

    // ---- Q fragment (B-operand): lane l15 holds Q row wave*16+l15
    int qr = wave * 16 + l15;
    size_t qpix = (size_t)(b * Hh + h0 + (qr >> 3)) * Wd + w0 + (qr & 7);
    bf16x8 aq = *(const bf16x8*)(Qh + qpix * HD + g * 8);
    bf16x8 kb;
#pragma unroll
    for (int j = 0; j < 8; ++j) kb[j] = (bf16)bkv[head * HD + g * 8 + j];
    __syncthreads();

    // ---- S^T = K @ Q^T : 16 kv-tiles; lane -> (kv = t*16+g*4+r, q = l15)
    f32x4 s[16];
    const f32x4 z = {0.f, 0.f, 0.f, 0.f};
    const bf16* kp = Kh + (p00 + l15) * HD + g * 8;
    if (interior) {
#pragma unroll
        for (int t = 0; t < 16; ++t) {
            bf16x8 kf = *(const bf16x8*)(kp + (size_t)t * Wd * HD);
            s[t] = mfma16(kf, aq, z);
        }
    } else {
        bool colok = ((unsigned)(w0 - 4 + l15) < (unsigned)Wd);
#pragma unroll
        for (int t = 0; t < 16; ++t) {
            int ph = h0 - 4 + t;                  // wave-uniform
            bf16x8 kf;
            if ((unsigned)ph < (unsigned)Hh) {
                kf = *(const bf16x8*)(kp + (size_t)t * Wd * HD);
                kf = colok ? kf : kb;
            } else {
                kf = kb;
            }
            s[t] = mfma16(kf, aq, z);
        }
    }

    // ---- softmax: each lane owns full row q=l15 (64 of 256 kv; rest in xor-16/32 lanes)
    const float sc = 0.17677669529663689f * 1.4426950408889634f; // scale * log2(e)
    float mr0 = fmaxf(s[0][0], s[0][1]), mr1 = fmaxf(s[0][2], s[0][3]);
#pragma unroll
    for (int t = 1; t < 16; ++t) {
        mr0 = fmaxf(mr0, fmaxf(s[t][0], s[t][1]));
        mr1 = fmaxf(mr1, fmaxf(s[t][2], s[t][3]));
    }
    float m = fmaxf(mr0, mr1);
    m = fmaxf(m, __shfl_xor(m, 16));
    m = fmaxf(m, __shfl_xor(m, 32));
    float nms = -m * sc;
    float sr0 = 0.f, sr1 = 0.f, sr2 = 0.f, sr3 = 0.f;
    int prow = wave * 16 + l15;
#pragma unroll
    for (int t = 0; t < 16; ++t) {
        float p0 = __builtin_amdgcn_exp2f(fmaf(s[t][0], sc, nms));
        float p1 = __builtin_amdgcn_exp2f(fmaf(s[t][1], sc, nms));
        float p2 = __builtin_amdgcn_exp2f(fmaf(s[t][2], sc, nms));
        float p3 = __builtin_amdgcn_exp2f(fmaf(s[t][3], sc, nms));
        sr0 += p0; sr1 += p1; sr2 += p2; sr3 += p3;
        unsigned pk = 0;
        pk = cvtpk_fp8<false>(p0, p1, pk);
        pk = cvtpk_fp8<true>(p2, p3, pk);
        *(unsigned*)&P8[prow * PS + t * 16 + g * 4] = pk;
    }
    float sum = (sr0 + sr1) + (sr2 + sr3);
    sum += __shfl_xor(sum, 16);
    sum += __shfl_xor(sum, 32);
    float inv = __builtin_amdgcn_rcpf(sum);
    __builtin_amdgcn_wave_barrier();   // P rows are wave-private; ordering only

    // ---- O = P @ V in fp8 (normalize at epilogue)
    f32x4 o[2] = {};
#pragma unroll
    for (int kk = 0; kk < 8; ++kk) {
        long long ap = *(const long long*)&P8[prow * PS + kk * 32 + g * 8];
#pragma unroll
        for (int nt = 0; nt < 2; ++nt) {
            long long bv = *(const long long*)&VT8[(nt * 16 + l15) * VS + kk * 32 + g * 8];
            o[nt] = mfma16f8(ap, bv, o[nt]);
        }
    }
    // inv for epilogue rows g*4+r lives in lanes with l15 == g*4+r (same g ok)
    float invr[4];
#pragma unroll
    for (int r = 0; r < 4; ++r)
        invr[r] = __shfl(inv, (lane & 48) | (g * 4 + r));
#pragma unroll
    for (int nt = 0; nt < 2; ++nt)
#pragma unroll
        for (int r = 0; r < 4; ++r) {
            int row = wave * 16 + g * 4 + r;
            size_t pix = (size_t)(b * Hh + h0 + (row >> 3)) * Wd + w0 + (row & 7);
            Oh[pix * HD + nt * 16 + l15] = (bf16)(o[nt][r] * invr[r]);
        }
}

// ---------------------------------------------------------------- K3: O-proj + residual (BHWC->BCHW)
// A is head-major AO[plane=c>>5][pix][32]; GEMM k-slice kk == plane.
__global__ __launch_bounds__(256) void k_out(const bf16* __restrict__ AO,
                                             const bf16* __restrict__ WoT,
                                             const float* __restrict__ bo,
                                             const float* __restrict__ x,
                                             float* __restrict__ out) {
    int row0 = blockIdx.x * 64;
    int tid = threadIdx.x, wave = tid >> 6, lane = tid & 63;
    int l15 = lane & 15, g = lane >> 4;
    int nb = wave * 48;
    f32x4 acc[4][3] = {};
    const bf16* Arow[4];
#pragma unroll
    for (int mt = 0; mt < 4; ++mt) Arow[mt] = AO + (size_t)(row0 + mt * 16 + l15) * HD + g * 8;
    const bf16* Wrow[3];
#pragma unroll
    for (int nt = 0; nt < 3; ++nt) Wrow[nt] = WoT + (size_t)(nb + nt * 16 + l15) * Cc + g * 8;
#pragma unroll
    for (int kk = 0; kk < 6; ++kk) {
        bf16x8 a[4];
#pragma unroll
        for (int mt = 0; mt < 4; ++mt)
            a[mt] = *(const bf16x8*)(Arow[mt] + (size_t)kk * Mtot * HD);
#pragma unroll
        for (int nt = 0; nt < 3; ++nt) {
            bf16x8 bb = *(const bf16x8*)(Wrow[nt] + kk * 32);
#pragma unroll
            for (int mt = 0; mt < 4; ++mt) acc[mt][nt] = mfma16(a[mt], bb, acc[mt][nt]);
        }
    }
    __shared__ float st[192 * 65];
#pragma unroll
    for (int nt = 0; nt < 3; ++nt) {
        float bval = bo[nb + nt * 16 + l15];
#pragma unroll
        for (int mt = 0; mt < 4; ++mt)
#pragma unroll
            for (int r = 0; r < 4; ++r) {
                int ccol = nb + nt * 16 + l15;
                int px = mt * 16 + g * 4 + r;
                st[ccol * 65 + px] = acc[mt][nt][r] + bval;
            }
    }
    __syncthreads();
    int bb2 = row0 / (Hh * Wd);
    int rem = row0 % (Hh * Wd);
    int h = rem / Wd, wstart = rem % Wd;
    for (int idx = tid; idx < 192 * 64; idx += 256) {
        int cc = idx >> 6, px = idx & 63;
        size_t ga = ((size_t)(bb2 * Cc + cc) * Hh + h) * Wd + wstart + px;
        out[ga] = st[cc * 65 + px] + x[ga];
    }
}

// ---------------------------------------------------------------- launch
extern "C" void kernel_launch(void* const* d_in, const int* in_sizes, int n_in,
                              void* d_out, int out_size, void* d_ws, size_t ws_size,
                              hipStream_t stream) {
    const float* x     = (const float*)d_in[0];
    const float* gamma = (const float*)d_in[1];
    const float* beta  = (const float*)d_in[2];
    const float* Wq    = (const float*)d_in[3];
    const float* bq    = (const float*)d_in[4];
    const float* Wkv   = (const float*)d_in[5];
    const float* bkv   = (const float*)d_in[6];
    const float* Wo    = (const float*)d_in[7];
    const float* bo    = (const float*)d_in[8];
    float* out = (float*)d_out;

    char* ws = (char*)d_ws;
    constexpr size_t PLANE = (size_t)Mtot * HD * 2;        // 16777216 B (bf16 plane)
    constexpr size_t QKSZ  = 12 * PLANE;                    // Q(6) + K(6)
    constexpr size_t V8SZ  = (size_t)NHd * Mtot * HD;       // 50331648 B (fp8)
    bf16*          QK  = (bf16*)(ws);
    unsigned char* V8  = (unsigned char*)(ws + QKSZ);
    bf16*          AO  = (bf16*)(ws + QKSZ + V8SZ);         // 6 bf16 planes
    bf16*          WT  = (bf16*)(ws + QKSZ + V8SZ + 6 * PLANE);
    bf16*          WoT = (bf16*)(ws + QKSZ + V8SZ + 6 * PLANE + 221184);

    k_prep<<<576, 256, 0, stream>>>(Wq, Wkv, Wo, WT, WoT);
    k_lnqkv<<<Mtot / 64, 256, 0, stream>>>(x, gamma, beta, WT, bq, bkv, QK, V8);
    k_attn<<<4096 * NHd, 256, 0, stream>>>(QK, V8, bkv, AO);
    k_out<<<Mtot / 64, 256, 0, stream>>>(AO, WoT, bo, x, out);
}